// Round 15
// baseline (120.099 us; speedup 1.0000x reference)
//
#include <hip/hip_runtime.h>
#include <hip/hip_bf16.h>
#include <math.h>

// Problem constants
#define BB 2
#define TT 2048
#define DD 1024
#define HH 16
#define HDD 64   // head dim
// qkv row stride = 3*DD = 3072 elems; per-head block of 192: [q(64)|k(64)|v(64)]

typedef __attribute__((ext_vector_type(8))) short short8;
typedef __attribute__((ext_vector_type(4))) float f32x4;
typedef __attribute__((ext_vector_type(16))) float f32x16;
typedef __attribute__((ext_vector_type(4))) unsigned u32x4;

#define PART_SPLIT 843           // entries in region A (xb/wqkvT), rest in d_out
#define PART_BYTES 17408         // 128x64 bf16 O (16384) + pad + 128 f32 l

__device__ __forceinline__ short f2bf(float f) {
  __hip_bfloat16 h = __float2bfloat16(f);
  return *reinterpret_cast<short*>(&h);
}

__device__ __forceinline__ float bf2f(short s) {
  unsigned u = ((unsigned)(unsigned short)s) << 16;
  return __builtin_bit_cast(float, u);
}

__device__ __forceinline__ unsigned cvtpk(float a, float b) {
  unsigned r;
  asm("v_cvt_pk_bf16_f32 %0, %1, %2" : "=v"(r) : "v"(a), "v"(b));
  return r;
}

// single-instruction v_exp_f32 (exp2); -inf -> 0 per ISA. OCML exp2f is ~5 instr.
__device__ __forceinline__ float exp2_fast(float x) {
#if __has_builtin(__builtin_amdgcn_exp2f)
  return __builtin_amdgcn_exp2f(x);
#else
  float r;
  asm("v_exp_f32 %0, %1" : "=v"(r) : "v"(x));
  return r;
#endif
}

__device__ __forceinline__ void gload_lds16(const void* g, void* l) {
  __builtin_amdgcn_global_load_lds(
      (const __attribute__((address_space(1))) unsigned int*)g,
      (__attribute__((address_space(3))) unsigned int*)l, 16, 0, 0);
}

// ---------- prep: x->bf16 + both weight transposes, one launch -------------------
__global__ __launch_bounds__(256) void prep(
    const float* __restrict__ x, const float* __restrict__ w_qkv,
    const float* __restrict__ w_out, short* __restrict__ xb,
    short* __restrict__ wqkvT, short* __restrict__ woutT) {
  __shared__ float tile[32][33];
  const int bid = blockIdx.x;
  const int tid = threadIdx.x;
  if (bid < 2048) {
    int i = bid * 256 + tid;
    const float4* pp = (const float4*)x + (size_t)i * 2;
    float4 a = pp[0], bq = pp[1];
    short8 o;
    o[0] = f2bf(a.x); o[1] = f2bf(a.y); o[2] = f2bf(a.z); o[3] = f2bf(a.w);
    o[4] = f2bf(bq.x); o[5] = f2bf(bq.y); o[6] = f2bf(bq.z); o[7] = f2bf(bq.w);
    *((short8*)xb + i) = o;
    return;
  }
  const float* W;
  short* WT;
  int R, C, bx, by;
  if (bid < 2048 + 3072) {
    int t = bid - 2048;
    bx = t % 96; by = t / 96;
    W = w_qkv; WT = wqkvT; R = 1024; C = 3072;
  } else {
    int t = bid - 5120;
    bx = t & 31; by = t >> 5;
    W = w_out; WT = woutT; R = 1024; C = 1024;
  }
  const int c0 = bx * 32, r0 = by * 32;
  const int tx = tid & 31, ty = tid >> 5;
#pragma unroll
  for (int i = 0; i < 32; i += 8)
    tile[ty + i][tx] = W[(size_t)(r0 + ty + i) * C + c0 + tx];
  __syncthreads();
#pragma unroll
  for (int i = 0; i < 32; i += 8)
    WT[(size_t)(c0 + ty + i) * R + r0 + tx] = f2bf(tile[tx][ty + i]);
}

// ---------- bf16 MFMA GEMM: C[M,N] = A[M,K] @ BT[N,K]^T -------------------------
// VFOLD (gemm1 only): the V 64-col block of each 192-col head group is written
// transposed to vtg [g][d][t] via an LDS bounce instead of to C (qkvb).
template <bool OUT_BF16, bool VFOLD>
__global__ __launch_bounds__(256) void gemm_bf16_mfma(
    const short* __restrict__ A, const short* __restrict__ BT,
    void* __restrict__ Cv, short* __restrict__ vtg, int M, int N, int K) {
  constexpr int BM = 128, BN = 128, BK = 64;
  __shared__ __align__(16) short As[BM * BK];
  __shared__ __align__(16) short Bs[BN * BK];

  const int nbx = N / BN;
  const int nwg = nbx * (M / BM);
  int bid = blockIdx.x;
  {
    int q = nwg >> 3;
    bid = (bid & 7) * q + (bid >> 3);
  }
  const int m0 = (bid / nbx) * BM;
  const int n0 = (bid % nbx) * BN;

  const int tid = threadIdx.x;
  const int lane = tid & 63;
  const int l15 = lane & 15;
  const int g4 = lane >> 4;
  const int wm = tid >> 7;
  const int wn = (tid >> 6) & 1;
  const int swz = (l15 & 7) << 4;

  f32x4 acc[4][4];
#pragma unroll
  for (int i = 0; i < 4; ++i)
#pragma unroll
    for (int j = 0; j < 4; ++j) acc[i][j] = (f32x4){0.f, 0.f, 0.f, 0.f};

  for (int k0 = 0; k0 < K; k0 += BK) {
    __syncthreads();
#pragma unroll
    for (int r = 0; r < 4; ++r) {
      int c = tid + r * 256;
      int row = c >> 3, cc = c & 7;
      int sc = (cc ^ (row & 7)) * 8;
      gload_lds16(A + (size_t)(m0 + row) * K + k0 + sc, (char*)As + c * 16);
    }
#pragma unroll
    for (int r = 0; r < 4; ++r) {
      int c = tid + r * 256;
      int row = c >> 3, cc = c & 7;
      int sc = (cc ^ (row & 7)) * 8;
      gload_lds16(BT + (size_t)(n0 + row) * K + k0 + sc, (char*)Bs + c * 16);
    }
    __syncthreads();

#pragma unroll
    for (int kk = 0; kk < 2; ++kk) {
      short8 af[4], bfr[4];
#pragma unroll
      for (int i = 0; i < 4; ++i) {
        int row = wm * 64 + i * 16 + l15;
        af[i] = *(const short8*)((const char*)As + row * 128 +
                                 (((kk * 4 + g4) << 4) ^ swz));
      }
#pragma unroll
      for (int j = 0; j < 4; ++j) {
        int row = wn * 64 + j * 16 + l15;
        bfr[j] = *(const short8*)((const char*)Bs + row * 128 +
                                  (((kk * 4 + g4) << 4) ^ swz));
      }
#pragma unroll
      for (int i = 0; i < 4; ++i)
#pragma unroll
        for (int j = 0; j < 4; ++j)
          acc[i][j] = __builtin_amdgcn_mfma_f32_16x16x32_bf16(
              af[i], bfr[j], acc[i][j], 0, 0, 0);
    }
  }

  // V-ness is uniform per wave-column: (n0/64 + wn) % 3 == 2  (192 = 3*64)
  const int q64 = n0 >> 6;
  const bool vwave = VFOLD && (((q64 + wn) % 3) == 2);

  if (!vwave) {
#pragma unroll
    for (int i = 0; i < 4; ++i) {
#pragma unroll
      for (int j = 0; j < 4; ++j) {
#pragma unroll
        for (int r = 0; r < 4; ++r) {
          size_t idx = (size_t)(m0 + wm * 64 + i * 16 + g4 * 4 + r) * N +
                       n0 + wn * 64 + j * 16 + l15;
          if (OUT_BF16)
            ((short*)Cv)[idx] = f2bf(acc[i][j][r]);
          else
            ((float*)Cv)[idx] = acc[i][j][r];
        }
      }
    }
  }

  if (VFOLD && (q64 % 3) != 0) {   // block contains a V 64-col block
    __syncthreads();               // main-loop LDS reads done; reuse As as Vt
    if (vwave) {
      // scatter acc -> Vt[d=0..63][t=0..127] bf16, XOR-slot swizzled rows (256B)
#pragma unroll
      for (int i = 0; i < 4; ++i) {
        int slot = wm * 8 + i * 2 + (g4 >> 1);
        int inoff = (g4 & 1) << 3;
#pragma unroll
        for (int j = 0; j < 4; ++j) {
          int d = j * 16 + l15;
          uint2 v = make_uint2(cvtpk(acc[i][j][0], acc[i][j][1]),
                               cvtpk(acc[i][j][2], acc[i][j][3]));
          *(uint2*)((char*)As + d * 256 + ((slot ^ (d & 7)) << 4) + inoff) = v;
        }
      }
    }
    __syncthreads();
    const int m3v = q64 % 3;
    const int wnV = (m3v == 2) ? 0 : 1;
    const int hV = (q64 + wnV) / 3;
    const int bb = m0 >> 11;
    const int tbase = m0 & 2047;
    short* vdst = vtg + ((size_t)(bb * HH + hV) * HDD) * TT + tbase;
#pragma unroll
    for (int it2 = 0; it2 < 4; ++it2) {
      int cc = tid + it2 * 256;
      int d = cc >> 4, s = cc & 15;
      short8 v = *(const short8*)((char*)As + d * 256 + ((s ^ (d & 7)) << 4));
      *(short8*)(vdst + (size_t)d * TT + s * 8) = v;
    }
  }
}

// Build PV A-fragment for k-slot from 8 p-values (T12: cvt_pk + permlane32_swap).
#define MAKE_PA(dst, P, B)                                                        \
  {                                                                               \
    unsigned a_, b_, c_, d_;                                                      \
    asm("v_cvt_pk_bf16_f32 %0, %1, %2" : "=v"(a_) : "v"(P[B + 0]), "v"(P[B + 1]));\
    asm("v_cvt_pk_bf16_f32 %0, %1, %2" : "=v"(b_) : "v"(P[B + 4]), "v"(P[B + 5]));\
    asm("v_permlane32_swap_b32 %0, %1" : "+v"(a_), "+v"(b_));                     \
    asm("v_cvt_pk_bf16_f32 %0, %1, %2" : "=v"(c_) : "v"(P[B + 2]), "v"(P[B + 3]));\
    asm("v_cvt_pk_bf16_f32 %0, %1, %2" : "=v"(d_) : "v"(P[B + 6]), "v"(P[B + 7]));\
    asm("v_permlane32_swap_b32 %0, %1" : "+v"(c_), "+v"(d_));                     \
    u32x4 uv_ = {a_, c_, b_, d_};                                                 \
    dst = __builtin_bit_cast(short8, uv_);                                        \
  }

// ---------- Flash attention v12: v10 structure; partials (m == 0) ---------------
__global__ __launch_bounds__(256) void attn_flash8(
    const short* __restrict__ qkv, const short* __restrict__ vtg,
    short* __restrict__ vals, char* __restrict__ partsA,
    char* __restrict__ partsB, float* __restrict__ mldiag) {
  const int bid = blockIdx.x;            // 0..2303
  const int xcd = bid & 7;
  const int j   = bid >> 3;              // 0..287
  const int g   = xcd + ((j & 3) << 3);  // bh group 0..31 (XCD-affine)
  const int c   = 71 - (j >> 2);         // chunk 0..71, big pairs first
  int kh = 0;
  while ((kh + 1) * (kh + 2) <= c) ++kh; // pair-group 0..7
  const int u   = c - kh * (kh + 1);
  const int dlt = (u >= kh + 1) ? 1 : 0;
  const int p   = 2 * kh + dlt;          // pair 0..15 (q-rows [p*128, p*128+128))
  const int ci  = u - dlt * (kh + 1);
  const int cnt = kh + 1;
  const int h = g & 15, b = g >> 4;
  const int nt  = 2 * p + 2;             // KV tiles of 64
  const int it0 = ci * nt / cnt;
  const int it1 = (ci + 1) * nt / cnt;

  const int tid = threadIdx.x;
  const int w = tid >> 6, lane = tid & 63;
  const int l31 = lane & 31;             // q within wave's 32-row subtile
  const int hi5 = lane >> 5;             // k-half selector
  const int sw7 = lane & 7;

  __shared__ __align__(16) short Ks[2][64 * 64];   // [k][d], swz slots
  __shared__ __align__(16) short Vs[2][64 * 64];   // [d][k], swz slots

  const size_t bhbase = (size_t)(b * TT) * 3072 + (size_t)h * 192;

  const float SSC = 0.18033688011112042f;  // 1/sqrt(64) * log2(e)

  // hoisted staging offsets
  const int c2 = tid + 256;
  const int r1 = tid >> 3, s1 = tid & 7;
  const int r2 = c2 >> 3,  s2 = c2 & 7;
  const size_t kgo1 = (size_t)r1 * 3072 + ((s1 ^ (r1 & 7)) * 8);
  const size_t kgo2 = (size_t)r2 * 3072 + ((s2 ^ (r2 & 7)) * 8);
  const size_t vgo1 = (size_t)r1 * TT + ((s1 ^ (r1 & 7)) * 8);
  const size_t vgo2 = (size_t)r2 * TT + ((s2 ^ (r2 & 7)) * 8);
  char* const ldsK0 = (char*)Ks[0] + tid * 16;
  char* const ldsK1 = (char*)Ks[1] + tid * 16;
  char* const ldsV0 = (char*)Vs[0] + tid * 16;
  char* const ldsV1 = (char*)Vs[1] + tid * 16;

  const short* kptr = qkv + bhbase + 64 + (size_t)(it0 * 64) * 3072;
  const short* vptr = vtg + (size_t)(b * HH + h) * HDD * TT + it0 * 64;

  auto STAGE = [&](int buf) {
    char* kl = buf ? ldsK1 : ldsK0;
    char* vl = buf ? ldsV1 : ldsV0;
    gload_lds16(kptr + kgo1, kl);
    gload_lds16(kptr + kgo2, kl + 4096);
    gload_lds16(vptr + vgo1, vl);
    gload_lds16(vptr + vgo2, vl + 4096);
    kptr += 64 * 3072;
    vptr += 64;
  };

  // Q fragments (B-operand: col q = l31, k-dim d = ks*16 + hi5*8 + j), SSC folded
  short8 qf[4];
  {
    const short* Qp = qkv + bhbase +
                      (size_t)(p * 128 + w * 32 + l31) * 3072 + hi5 * 8;
#pragma unroll
    for (int ks = 0; ks < 4; ++ks) {
      short8 raw = *(const short8*)(Qp + ks * 16);
#pragma unroll
      for (int jj = 0; jj < 8; ++jj) qf[ks][jj] = f2bf(bf2f(raw[jj]) * SSC);
    }
  }

  float lsum = 0.f;                 // lane-partial row sum for q = l31
  f32x16 oacc0 = 0.f, oacc1 = 0.f;  // O[q-rows][d: 0-31 / 32-63]

  STAGE(0);
  int cur = 0;

#pragma unroll 1
  for (int it = it0; it < it1; ++it) {
    __syncthreads();  // drains vmcnt: buf[cur] staged; buf[cur^1] reads done
    if (it + 1 < it1) STAGE(cur ^ 1);

    const char* ksb = cur ? (const char*)Ks[1] : (const char*)Ks[0];
    const char* vsb = cur ? (const char*)Vs[1] : (const char*)Vs[0];

    // ---- QK^T (swapped): S^T[k][q]; A = K rows (32/k-subtile), B = Q ----
    f32x16 sA = 0.f, sB = 0.f;       // k 0-31 / 32-63 of this KV-tile
    __builtin_amdgcn_s_setprio(1);
#pragma unroll
    for (int ks = 0; ks < 4; ++ks) {
      int slot = (ks * 2 + hi5);
      const char* kb0 = ksb + l31 * 128 + ((slot ^ sw7) << 4);
      short8 kf0 = *(const short8*)(kb0);
      short8 kf1 = *(const short8*)(kb0 + 32 * 128);
      sA = __builtin_amdgcn_mfma_f32_32x32x16_bf16(kf0, qf[ks], sA, 0, 0, 0);
      sB = __builtin_amdgcn_mfma_f32_32x32x16_bf16(kf1, qf[ks], sB, 0, 0, 0);
    }
    __builtin_amdgcn_s_setprio(0);

    // ---- causal mask (per-wave uniform branch) ----
    if (it * 64 + 63 > p * 128 + w * 32) {
      const int qg = p * 128 + w * 32 + l31;
#pragma unroll
      for (int r = 0; r < 16; ++r) {
        int kr = it * 64 + (r & 3) + 8 * (r >> 2) + 4 * hi5;
        if (kr > qg) sA[r] = -INFINITY;
        if (kr + 32 > qg) sB[r] = -INFINITY;
      }
    }

    // ---- softmax numerator: p = exp2(s) raw (scale cancels in O/lsum) ----
    float ts0 = 0.f, ts1 = 0.f, ts2 = 0.f, ts3 = 0.f;
#pragma unroll
    for (int r = 0; r < 16; r += 2) {
      float eA0 = exp2_fast(sA[r]);
      float eA1 = exp2_fast(sA[r + 1]);
      float eB0 = exp2_fast(sB[r]);
      float eB1 = exp2_fast(sB[r + 1]);
      sA[r] = eA0; sA[r + 1] = eA1;
      sB[r] = eB0; sB[r + 1] = eB1;
      ts0 += eA0; ts1 += eA1;
      ts2 += eB0; ts3 += eB1;
    }
    lsum += (ts0 + ts1) + (ts2 + ts3);

    // ---- build PV A-frags in-register (k-slots 0..3) ----
    short8 pa0, pa1, pa2, pa3;
    MAKE_PA(pa0, sA, 0);
    MAKE_PA(pa1, sA, 8);
    MAKE_PA(pa2, sB, 0);
    MAKE_PA(pa3, sB, 8);

    // ---- PV: O[32q][64d] += P[32q][64k] . V[64k][64d] ----
    __builtin_amdgcn_s_setprio(1);
#pragma unroll
    for (int dtile = 0; dtile < 2; ++dtile) {
      const char* vb = vsb + (dtile * 32 + l31) * 128;
      short8 vf0 = *(const short8*)(vb + (((0 * 2 + hi5) ^ sw7) << 4));
      short8 vf1 = *(const short8*)(vb + (((1 * 2 + hi5) ^ sw7) << 4));
      short8 vf2 = *(const short8*)(vb + (((2 * 2 + hi5) ^ sw7) << 4));
      short8 vf3 = *(const short8*)(vb + (((3 * 2 + hi5) ^ sw7) << 4));
      if (dtile == 0) {
        oacc0 = __builtin_amdgcn_mfma_f32_32x32x16_bf16(pa0, vf0, oacc0, 0, 0, 0);
        oacc0 = __builtin_amdgcn_mfma_f32_32x32x16_bf16(pa1, vf1, oacc0, 0, 0, 0);
        oacc0 = __builtin_amdgcn_mfma_f32_32x32x16_bf16(pa2, vf2, oacc0, 0, 0, 0);
        oacc0 = __builtin_amdgcn_mfma_f32_32x32x16_bf16(pa3, vf3, oacc0, 0, 0, 0);
      } else {
        oacc1 = __builtin_amdgcn_mfma_f32_32x32x16_bf16(pa0, vf0, oacc1, 0, 0, 0);
        oacc1 = __builtin_amdgcn_mfma_f32_32x32x16_bf16(pa1, vf1, oacc1, 0, 0, 0);
        oacc1 = __builtin_amdgcn_mfma_f32_32x32x16_bf16(pa2, vf2, oacc1, 0, 0, 0);
        oacc1 = __builtin_amdgcn_mfma_f32_32x32x16_bf16(pa3, vf3, oacc1, 0, 0, 0);
      }
    }
    __builtin_amdgcn_s_setprio(0);

    cur ^= 1;
  }

  // ---- finalize lsum: lanes l and l+32 hold complementary k-halves ----
  lsum += __shfl_xor(lsum, 32);

  // ---- epilogue (chunk roles; m == 0 everywhere with raw exp2) ----
  const size_t gTT = (size_t)g * TT;
  if (cnt == 1) {
    float inv = 1.f / lsum;
#pragma unroll
    for (int r = 0; r < 16; ++r) {
      int qrow = (r & 3) + 8 * (r >> 2) + 4 * hi5;
      float iq = __shfl(inv, qrow, 32);
      size_t vr = (gTT + p * 128 + w * 32 + qrow) * HDD;
      vals[vr + l31] = f2bf(oacc0[r] * iq);
      vals[vr + 32 + l31] = f2bf(oacc1[r] * iq);
    }
  } else if (ci == cnt - 1) {
    // diagonal chunk: unnormalized O -> vals; l -> mldiag
#pragma unroll
    for (int r = 0; r < 16; ++r) {
      int qrow = (r & 3) + 8 * (r >> 2) + 4 * hi5;
      size_t vr = (gTT + p * 128 + w * 32 + qrow) * HDD;
      vals[vr + l31] = f2bf(oacc0[r]);
      vals[vr + 32 + l31] = f2bf(oacc1[r]);
    }
    if (lane < 32) {
      int base = (g * 16 + p) * 256;
      int qr = w * 32 + lane;
      mldiag[base + 128 + qr] = lsum;
    }
  } else {
    // producer chunk: bf16 partial (O, l)
    const int PL0 = kh * (kh - 1) + dlt * kh;
    const int e = g * 56 + PL0 + ci;
    char* pp = (e < PART_SPLIT) ? (partsA + (size_t)e * PART_BYTES)
                                : (partsB + (size_t)(e - PART_SPLIT) * PART_BYTES);
    short* po = (short*)pp;
#pragma unroll
    for (int r = 0; r < 16; ++r) {
      int qrow = (r & 3) + 8 * (r >> 2) + 4 * hi5;
      int rr = w * 32 + qrow;
      po[rr * 64 + l31] = f2bf(oacc0[r]);
      po[rr * 64 + 32 + l31] = f2bf(oacc1[r]);
    }
    if (lane < 32) {
      int qr = w * 32 + lane;
      *(float*)(pp + 16896 + qr * 4) = lsum;
    }
  }
}

// ---------- merge partial chunks into vals (plain sums; m == 0) -----------------
// grid (14, 32): p = 2+bx, g = by. 256 thr: row = tid>>1 (128), dh = (tid&1)*32.
__global__ __launch_bounds__(256) void attn_merge3(
    short* __restrict__ vals, const char* __restrict__ partsA,
    const char* __restrict__ partsB, const float* __restrict__ mldiag) {
  const int p = 2 + blockIdx.x;
  const int g = blockIdx.y;
  const int k = p >> 1, dlt = p & 1;
  const int np = k;                       // producers = cnt-1
  const int PL = k * (k - 1) + dlt * k;
  const int e0 = g * 56 + PL;
  const int tid = threadIdx.x;
  const int row = tid >> 1;
  const int dh = (tid & 1) << 5;

  float lacc = mldiag[(g * 16 + p) * 256 + 128 + row];

  size_t vbase = ((size_t)g * TT + p * 128 + row) * HDD + dh;
  float o[32];
  {
    short8 v0 = *(const short8*)(vals + vbase);
    short8 v1 = *(const short8*)(vals + vbase + 8);
    short8 v2 = *(const short8*)(vals + vbase + 16);
    short8 v3 = *(const short8*)(vals + vbase + 24);
#pragma unroll
    for (int jj = 0; jj < 8; ++jj) {
      o[jj] = bf2f(v0[jj]);
      o[8 + jj] = bf2f(v1[jj]);
      o[16 + jj] = bf2f(v2[jj]);
      o[24 + jj] = bf2f(v3[jj]);
    }
  }
  for (int e = 0; e < np; ++e) {
    int ee = e0 + e;
    const char* pp = (ee < PART_SPLIT)
                         ? (partsA + (size_t)ee * PART_BYTES)
                         : (partsB + (size_t)(ee - PART_SPLIT) * PART_BYTES);
    lacc += *(const float*)(pp + 16896 + row * 4);
    const short* po = (const short*)pp + row * 64 + dh;
    short8 v0 = *(const short8*)po;
    short8 v1 = *(const short8*)(po + 8);
    short8 v2 = *(const short8*)(po + 16);
    short8 v3 = *(const short8*)(po + 24);
#pragma unroll
    for (int jj = 0; jj < 8; ++jj) {
      o[jj] += bf2f(v0[jj]);
      o[8 + jj] += bf2f(v1[jj]);
      o[16 + jj] += bf2f(v2[jj]);
      o[24 + jj] += bf2f(v3[jj]);
    }
  }
  float inv = 1.f / lacc;
  short8 w0, w1, w2, w3;
#pragma unroll
  for (int jj = 0; jj < 8; ++jj) {
    w0[jj] = f2bf(o[jj] * inv);
    w1[jj] = f2bf(o[8 + jj] * inv);
    w2[jj] = f2bf(o[16 + jj] * inv);
    w3[jj] = f2bf(o[24 + jj] * inv);
  }
  *(short8*)(vals + vbase) = w0;
  *(short8*)(vals + vbase + 8) = w1;
  *(short8*)(vals + vbase + 16) = w2;
  *(short8*)(vals + vbase + 24) = w3;
}

extern "C" void kernel_launch(void* const* d_in, const int* in_sizes, int n_in,
                              void* d_out, int out_size, void* d_ws, size_t ws_size,
                              hipStream_t stream) {
  const float* x     = (const float*)d_in[0];   // (B, T, D)
  const float* w_qkv = (const float*)d_in[1];   // (D, 3D)
  const float* w_out = (const float*)d_in[2];   // (D, D)
  float* out = (float*)d_out;                   // (B, T, D) fp32

  // workspace layout (bytes)
  char* ws = (char*)d_ws;
  short* qkvb  = (short*)(ws);                       // 25.17 MB
  short* valsb = (short*)(ws + 25165824);            //  8.39 MB
  short* xb    = (short*)(ws + 33554432);            //  8.39 MB (dead after gemm1)
  short* wqkvT = (short*)(ws + 41943040);            //  6.29 MB (dead after gemm1)
  short* woutT = (short*)(ws + 48234496);            //  2.10 MB
  short* vtg   = (short*)(ws + 50331648);            //  8.39 MB (V^T [g][d][t])
  char*  partsA = ws + 33554432;                     // 14.67 MB (over xb/wqkvT)
  char*  partsB = (char*)d_out;                      // d_out scratch pre-gemm2
  float* mldiag = (float*)(ws + 58720256);           //  0.50 MB

  const int M = BB * TT;  // 4096

  // 1) prep: x->bf16 + both weight transposes
  prep<<<6144, 256, 0, stream>>>(x, w_qkv, w_out, xb, wqkvT, woutT);

  // 2) qkv = x @ w_qkv (bf16), V-block written transposed to vtg in-epilogue
  gemm_bf16_mfma<true, true><<<(M / 128) * (3 * DD / 128), 256, 0, stream>>>(
      xb, wqkvT, qkvb, vtg, M, 3 * DD, DD);

  // 3) flash attention v12 + merge (separate kernel: device-wide sync boundary)
  attn_flash8<<<2304, 256, 0, stream>>>(qkvb, vtg, valsb, partsA, partsB, mldiag);
  {
    dim3 g(14, 32);
    attn_merge3<<<g, 256, 0, stream>>>(valsb, partsA, partsB, mldiag);
  }

  // 4) out = vals @ w_out (fp32 out)
  gemm_bf16_mfma<false, false><<<(M / 128) * (DD / 128), 256, 0, stream>>>(
      valsb, woutT, out, nullptr, M, DD, DD);
}

// Round 16
// 111.181 us; speedup vs baseline: 1.0802x; 1.0802x over previous
//
#include <hip/hip_runtime.h>
#include <hip/hip_bf16.h>
#include <math.h>

// Problem constants
#define BB 2
#define TT 2048
#define DD 1024
#define HH 16
#define HDD 64   // head dim
// qkv row stride = 3*DD = 3072 elems; per-head block of 192: [q(64)|k(64)|v(64)]

typedef __attribute__((ext_vector_type(8))) short short8;
typedef __attribute__((ext_vector_type(4))) float f32x4;
typedef __attribute__((ext_vector_type(16))) float f32x16;
typedef __attribute__((ext_vector_type(4))) unsigned u32x4;

#define PART_SPLIT 843           // entries in region A (xb/wqkvT), rest in d_out
#define PART_BYTES 17408         // 128x64 bf16 O (16384) + pad + 128 f32 l

__device__ __forceinline__ short f2bf(float f) {
  __hip_bfloat16 h = __float2bfloat16(f);
  return *reinterpret_cast<short*>(&h);
}

__device__ __forceinline__ float bf2f(short s) {
  unsigned u = ((unsigned)(unsigned short)s) << 16;
  return __builtin_bit_cast(float, u);
}

// single-instruction v_exp_f32 (exp2); -inf -> 0 per ISA. OCML exp2f is ~5 instr.
__device__ __forceinline__ float exp2_fast(float x) {
#if __has_builtin(__builtin_amdgcn_exp2f)
  return __builtin_amdgcn_exp2f(x);
#else
  float r;
  asm("v_exp_f32 %0, %1" : "=v"(r) : "v"(x));
  return r;
#endif
}

__device__ __forceinline__ void gload_lds16(const void* g, void* l) {
  __builtin_amdgcn_global_load_lds(
      (const __attribute__((address_space(1))) unsigned int*)g,
      (__attribute__((address_space(3))) unsigned int*)l, 16, 0, 0);
}

// ---------- prep: x->bf16 + both weight transposes, one launch -------------------
__global__ __launch_bounds__(256) void prep(
    const float* __restrict__ x, const float* __restrict__ w_qkv,
    const float* __restrict__ w_out, short* __restrict__ xb,
    short* __restrict__ wqkvT, short* __restrict__ woutT) {
  __shared__ float tile[32][33];
  const int bid = blockIdx.x;
  const int tid = threadIdx.x;
  if (bid < 2048) {
    int i = bid * 256 + tid;
    const float4* pp = (const float4*)x + (size_t)i * 2;
    float4 a = pp[0], bq = pp[1];
    short8 o;
    o[0] = f2bf(a.x); o[1] = f2bf(a.y); o[2] = f2bf(a.z); o[3] = f2bf(a.w);
    o[4] = f2bf(bq.x); o[5] = f2bf(bq.y); o[6] = f2bf(bq.z); o[7] = f2bf(bq.w);
    *((short8*)xb + i) = o;
    return;
  }
  const float* W;
  short* WT;
  int R, C, bx, by;
  if (bid < 2048 + 3072) {
    int t = bid - 2048;
    bx = t % 96; by = t / 96;
    W = w_qkv; WT = wqkvT; R = 1024; C = 3072;
  } else {
    int t = bid - 5120;
    bx = t & 31; by = t >> 5;
    W = w_out; WT = woutT; R = 1024; C = 1024;
  }
  const int c0 = bx * 32, r0 = by * 32;
  const int tx = tid & 31, ty = tid >> 5;
#pragma unroll
  for (int i = 0; i < 32; i += 8)
    tile[ty + i][tx] = W[(size_t)(r0 + ty + i) * C + c0 + tx];
  __syncthreads();
#pragma unroll
  for (int i = 0; i < 32; i += 8)
    WT[(size_t)(c0 + ty + i) * R + r0 + tx] = f2bf(tile[tx][ty + i]);
}

// ---------- V slice of qkv (bf16) -> V^T [b][h][d][t] ---------------------------
__global__ __launch_bounds__(256) void vtrans(const short* __restrict__ qkv,
                                              short* __restrict__ vtg) {
  const int t0 = blockIdx.x * 64;
  const int h = blockIdx.y, b = blockIdx.z;
  __shared__ __align__(16) short sm[64 * 64];
  const int tid = threadIdx.x;
  const short* Vg = qkv + (size_t)(b * TT) * 3072 + h * 192 + 128;
#pragma unroll
  for (int r2 = 0; r2 < 2; ++r2) {
    int c = tid + r2 * 256;
    int t = c >> 3, d0 = (c & 7) * 8;
    short8 v = *(const short8*)(Vg + (size_t)(t0 + t) * 3072 + d0);
#pragma unroll
    for (int j = 0; j < 8; ++j) {
      int d = d0 + j;
      int byte = (d << 7) + ((t * 2) ^ (((d >> 3) & 7) << 4));
      *(short*)((char*)sm + byte) = v[j];
    }
  }
  __syncthreads();
  short* outp = vtg + (size_t)(b * HH + h) * HDD * TT + t0;
#pragma unroll
  for (int r2 = 0; r2 < 2; ++r2) {
    int c = tid + r2 * 256;
    int d = c >> 3, tc = c & 7;
    int byte = (d << 7) + ((tc ^ ((d >> 3) & 7)) << 4);
    short8 v = *(const short8*)((char*)sm + byte);
    *(short8*)(outp + (size_t)d * TT + tc * 8) = v;
  }
}

// ---------- bf16 MFMA GEMM: C[M,N] = A[M,K] @ BT[N,K]^T -------------------------
template <bool OUT_BF16>
__global__ __launch_bounds__(256) void gemm_bf16_mfma(
    const short* __restrict__ A, const short* __restrict__ BT,
    void* __restrict__ Cv, int M, int N, int K) {
  constexpr int BM = 128, BN = 128, BK = 64;
  __shared__ __align__(16) short As[BM * BK];
  __shared__ __align__(16) short Bs[BN * BK];

  const int nbx = N / BN;
  const int nwg = nbx * (M / BM);
  int bid = blockIdx.x;
  {
    int q = nwg >> 3;
    bid = (bid & 7) * q + (bid >> 3);
  }
  const int m0 = (bid / nbx) * BM;
  const int n0 = (bid % nbx) * BN;

  const int tid = threadIdx.x;
  const int lane = tid & 63;
  const int l15 = lane & 15;
  const int g4 = lane >> 4;
  const int wm = tid >> 7;
  const int wn = (tid >> 6) & 1;
  const int swz = (l15 & 7) << 4;

  f32x4 acc[4][4];
#pragma unroll
  for (int i = 0; i < 4; ++i)
#pragma unroll
    for (int j = 0; j < 4; ++j) acc[i][j] = (f32x4){0.f, 0.f, 0.f, 0.f};

  for (int k0 = 0; k0 < K; k0 += BK) {
    __syncthreads();
#pragma unroll
    for (int r = 0; r < 4; ++r) {
      int c = tid + r * 256;
      int row = c >> 3, cc = c & 7;
      int sc = (cc ^ (row & 7)) * 8;
      gload_lds16(A + (size_t)(m0 + row) * K + k0 + sc, (char*)As + c * 16);
    }
#pragma unroll
    for (int r = 0; r < 4; ++r) {
      int c = tid + r * 256;
      int row = c >> 3, cc = c & 7;
      int sc = (cc ^ (row & 7)) * 8;
      gload_lds16(BT + (size_t)(n0 + row) * K + k0 + sc, (char*)Bs + c * 16);
    }
    __syncthreads();

#pragma unroll
    for (int kk = 0; kk < 2; ++kk) {
      short8 af[4], bfr[4];
#pragma unroll
      for (int i = 0; i < 4; ++i) {
        int row = wm * 64 + i * 16 + l15;
        af[i] = *(const short8*)((const char*)As + row * 128 +
                                 (((kk * 4 + g4) << 4) ^ swz));
      }
#pragma unroll
      for (int j = 0; j < 4; ++j) {
        int row = wn * 64 + j * 16 + l15;
        bfr[j] = *(const short8*)((const char*)Bs + row * 128 +
                                  (((kk * 4 + g4) << 4) ^ swz));
      }
#pragma unroll
      for (int i = 0; i < 4; ++i)
#pragma unroll
        for (int j = 0; j < 4; ++j)
          acc[i][j] = __builtin_amdgcn_mfma_f32_16x16x32_bf16(
              af[i], bfr[j], acc[i][j], 0, 0, 0);
    }
  }

#pragma unroll
  for (int i = 0; i < 4; ++i) {
#pragma unroll
    for (int j = 0; j < 4; ++j) {
#pragma unroll
      for (int r = 0; r < 4; ++r) {
        size_t idx = (size_t)(m0 + wm * 64 + i * 16 + g4 * 4 + r) * N +
                     n0 + wn * 64 + j * 16 + l15;
        if (OUT_BF16)
          ((short*)Cv)[idx] = f2bf(acc[i][j][r]);
        else
          ((float*)Cv)[idx] = acc[i][j][r];
      }
    }
  }
}

// Build PV A-fragment for k-slot from 8 p-values (T12: cvt_pk + permlane32_swap).
#define MAKE_PA(dst, P, B)                                                        \
  {                                                                               \
    unsigned a_, b_, c_, d_;                                                      \
    asm("v_cvt_pk_bf16_f32 %0, %1, %2" : "=v"(a_) : "v"(P[B + 0]), "v"(P[B + 1]));\
    asm("v_cvt_pk_bf16_f32 %0, %1, %2" : "=v"(b_) : "v"(P[B + 4]), "v"(P[B + 5]));\
    asm("v_permlane32_swap_b32 %0, %1" : "+v"(a_), "+v"(b_));                     \
    asm("v_cvt_pk_bf16_f32 %0, %1, %2" : "=v"(c_) : "v"(P[B + 2]), "v"(P[B + 3]));\
    asm("v_cvt_pk_bf16_f32 %0, %1, %2" : "=v"(d_) : "v"(P[B + 6]), "v"(P[B + 7]));\
    asm("v_permlane32_swap_b32 %0, %1" : "+v"(c_), "+v"(d_));                     \
    u32x4 uv_ = {a_, c_, b_, d_};                                                 \
    dst = __builtin_bit_cast(short8, uv_);                                        \
  }

// ---------- Flash attention: 32x32 MFMA, in-register P, raw exp2, split-KV ------
__global__ __launch_bounds__(256) void attn_flash8(
    const short* __restrict__ qkv, const short* __restrict__ vtg,
    short* __restrict__ vals, char* __restrict__ partsA,
    char* __restrict__ partsB, float* __restrict__ mldiag) {
  const int bid = blockIdx.x;            // 0..2303
  const int xcd = bid & 7;
  const int j   = bid >> 3;              // 0..287
  const int g   = xcd + ((j & 3) << 3);  // bh group 0..31 (XCD-affine)
  const int c   = 71 - (j >> 2);         // chunk 0..71, big pairs first
  int kh = 0;
  while ((kh + 1) * (kh + 2) <= c) ++kh; // pair-group 0..7
  const int u   = c - kh * (kh + 1);
  const int dlt = (u >= kh + 1) ? 1 : 0;
  const int p   = 2 * kh + dlt;          // pair 0..15 (q-rows [p*128, p*128+128))
  const int ci  = u - dlt * (kh + 1);
  const int cnt = kh + 1;
  const int h = g & 15, b = g >> 4;
  const int nt  = 2 * p + 2;             // KV tiles of 64
  const int it0 = ci * nt / cnt;
  const int it1 = (ci + 1) * nt / cnt;

  const int tid = threadIdx.x;
  const int w = tid >> 6, lane = tid & 63;
  const int l31 = lane & 31;             // q within wave's 32-row subtile
  const int hi5 = lane >> 5;             // k-half selector
  const int sw7 = lane & 7;

  __shared__ __align__(16) short Ks[2][64 * 64];   // [k][d], swz slots
  __shared__ __align__(16) short Vs[2][64 * 64];   // [d][k], swz slots

  const size_t bhbase = (size_t)(b * TT) * 3072 + (size_t)h * 192;

  const float SSC = 0.18033688011112042f;  // 1/sqrt(64) * log2(e)

  // hoisted staging offsets
  const int c2 = tid + 256;
  const int r1 = tid >> 3, s1 = tid & 7;
  const int r2 = c2 >> 3,  s2 = c2 & 7;
  const size_t kgo1 = (size_t)r1 * 3072 + ((s1 ^ (r1 & 7)) * 8);
  const size_t kgo2 = (size_t)r2 * 3072 + ((s2 ^ (r2 & 7)) * 8);
  const size_t vgo1 = (size_t)r1 * TT + ((s1 ^ (r1 & 7)) * 8);
  const size_t vgo2 = (size_t)r2 * TT + ((s2 ^ (r2 & 7)) * 8);
  char* const ldsK0 = (char*)Ks[0] + tid * 16;
  char* const ldsK1 = (char*)Ks[1] + tid * 16;
  char* const ldsV0 = (char*)Vs[0] + tid * 16;
  char* const ldsV1 = (char*)Vs[1] + tid * 16;

  const short* kptr = qkv + bhbase + 64 + (size_t)(it0 * 64) * 3072;
  const short* vptr = vtg + (size_t)(b * HH + h) * HDD * TT + it0 * 64;

  auto STAGE = [&](int buf) {
    char* kl = buf ? ldsK1 : ldsK0;
    char* vl = buf ? ldsV1 : ldsV0;
    gload_lds16(kptr + kgo1, kl);
    gload_lds16(kptr + kgo2, kl + 4096);
    gload_lds16(vptr + vgo1, vl);
    gload_lds16(vptr + vgo2, vl + 4096);
    kptr += 64 * 3072;
    vptr += 64;
  };

  // Q fragments (B-operand: col q = l31, k-dim d = ks*16 + hi5*8 + j), SSC folded
  short8 qf[4];
  {
    const short* Qp = qkv + bhbase +
                      (size_t)(p * 128 + w * 32 + l31) * 3072 + hi5 * 8;
#pragma unroll
    for (int ks = 0; ks < 4; ++ks) {
      short8 raw = *(const short8*)(Qp + ks * 16);
#pragma unroll
      for (int jj = 0; jj < 8; ++jj) qf[ks][jj] = f2bf(bf2f(raw[jj]) * SSC);
    }
  }

  float lsum = 0.f;                 // lane-partial row sum for q = l31
  f32x16 oacc0 = 0.f, oacc1 = 0.f;  // O[q-rows][d: 0-31 / 32-63]

  STAGE(0);
  int cur = 0;

#pragma unroll 1
  for (int it = it0; it < it1; ++it) {
    __syncthreads();  // drains vmcnt: buf[cur] staged; buf[cur^1] reads done
    if (it + 1 < it1) STAGE(cur ^ 1);

    const char* ksb = cur ? (const char*)Ks[1] : (const char*)Ks[0];
    const char* vsb = cur ? (const char*)Vs[1] : (const char*)Vs[0];

    // ---- QK^T (swapped): S^T[k][q]; A = K rows (32/k-subtile), B = Q ----
    f32x16 sA = 0.f, sB = 0.f;       // k 0-31 / 32-63 of this KV-tile
    __builtin_amdgcn_s_setprio(1);
#pragma unroll
    for (int ks = 0; ks < 4; ++ks) {
      int slot = (ks * 2 + hi5);
      const char* kb0 = ksb + l31 * 128 + ((slot ^ sw7) << 4);
      short8 kf0 = *(const short8*)(kb0);
      short8 kf1 = *(const short8*)(kb0 + 32 * 128);
      sA = __builtin_amdgcn_mfma_f32_32x32x16_bf16(kf0, qf[ks], sA, 0, 0, 0);
      sB = __builtin_amdgcn_mfma_f32_32x32x16_bf16(kf1, qf[ks], sB, 0, 0, 0);
    }
    __builtin_amdgcn_s_setprio(0);

    // ---- causal mask (per-wave uniform branch) ----
    if (it * 64 + 63 > p * 128 + w * 32) {
      const int qg = p * 128 + w * 32 + l31;
#pragma unroll
      for (int r = 0; r < 16; ++r) {
        int kr = it * 64 + (r & 3) + 8 * (r >> 2) + 4 * hi5;
        if (kr > qg) sA[r] = -INFINITY;
        if (kr + 32 > qg) sB[r] = -INFINITY;
      }
    }

    // ---- softmax numerator: p = exp2(s) raw (scale cancels in O/lsum) ----
    float ts0 = 0.f, ts1 = 0.f, ts2 = 0.f, ts3 = 0.f;
#pragma unroll
    for (int r = 0; r < 16; r += 2) {
      float eA0 = exp2_fast(sA[r]);
      float eA1 = exp2_fast(sA[r + 1]);
      float eB0 = exp2_fast(sB[r]);
      float eB1 = exp2_fast(sB[r + 1]);
      sA[r] = eA0; sA[r + 1] = eA1;
      sB[r] = eB0; sB[r + 1] = eB1;
      ts0 += eA0; ts1 += eA1;
      ts2 += eB0; ts3 += eB1;
    }
    lsum += (ts0 + ts1) + (ts2 + ts3);

    // ---- build PV A-frags in-register (k-slots 0..3) ----
    short8 pa0, pa1, pa2, pa3;
    MAKE_PA(pa0, sA, 0);
    MAKE_PA(pa1, sA, 8);
    MAKE_PA(pa2, sB, 0);
    MAKE_PA(pa3, sB, 8);

    // ---- PV: O[32q][64d] += P[32q][64k] . V[64k][64d] ----
    __builtin_amdgcn_s_setprio(1);
#pragma unroll
    for (int dtile = 0; dtile < 2; ++dtile) {
      const char* vb = vsb + (dtile * 32 + l31) * 128;
      short8 vf0 = *(const short8*)(vb + (((0 * 2 + hi5) ^ sw7) << 4));
      short8 vf1 = *(const short8*)(vb + (((1 * 2 + hi5) ^ sw7) << 4));
      short8 vf2 = *(const short8*)(vb + (((2 * 2 + hi5) ^ sw7) << 4));
      short8 vf3 = *(const short8*)(vb + (((3 * 2 + hi5) ^ sw7) << 4));
      if (dtile == 0) {
        oacc0 = __builtin_amdgcn_mfma_f32_32x32x16_bf16(pa0, vf0, oacc0, 0, 0, 0);
        oacc0 = __builtin_amdgcn_mfma_f32_32x32x16_bf16(pa1, vf1, oacc0, 0, 0, 0);
        oacc0 = __builtin_amdgcn_mfma_f32_32x32x16_bf16(pa2, vf2, oacc0, 0, 0, 0);
        oacc0 = __builtin_amdgcn_mfma_f32_32x32x16_bf16(pa3, vf3, oacc0, 0, 0, 0);
      } else {
        oacc1 = __builtin_amdgcn_mfma_f32_32x32x16_bf16(pa0, vf0, oacc1, 0, 0, 0);
        oacc1 = __builtin_amdgcn_mfma_f32_32x32x16_bf16(pa1, vf1, oacc1, 0, 0, 0);
        oacc1 = __builtin_amdgcn_mfma_f32_32x32x16_bf16(pa2, vf2, oacc1, 0, 0, 0);
        oacc1 = __builtin_amdgcn_mfma_f32_32x32x16_bf16(pa3, vf3, oacc1, 0, 0, 0);
      }
    }
    __builtin_amdgcn_s_setprio(0);

    cur ^= 1;
  }

  // ---- finalize lsum: lanes l and l+32 hold complementary k-halves ----
  lsum += __shfl_xor(lsum, 32);

  // ---- epilogue (chunk roles; m == 0 everywhere with raw exp2) ----
  const size_t gTT = (size_t)g * TT;
  if (cnt == 1) {
    float inv = 1.f / lsum;
#pragma unroll
    for (int r = 0; r < 16; ++r) {
      int qrow = (r & 3) + 8 * (r >> 2) + 4 * hi5;
      float iq = __shfl(inv, qrow, 32);
      size_t vr = (gTT + p * 128 + w * 32 + qrow) * HDD;
      vals[vr + l31] = f2bf(oacc0[r] * iq);
      vals[vr + 32 + l31] = f2bf(oacc1[r] * iq);
    }
  } else if (ci == cnt - 1) {
    // diagonal chunk: unnormalized O -> vals; l -> mldiag
#pragma unroll
    for (int r = 0; r < 16; ++r) {
      int qrow = (r & 3) + 8 * (r >> 2) + 4 * hi5;
      size_t vr = (gTT + p * 128 + w * 32 + qrow) * HDD;
      vals[vr + l31] = f2bf(oacc0[r]);
      vals[vr + 32 + l31] = f2bf(oacc1[r]);
    }
    if (lane < 32) {
      int base = (g * 16 + p) * 256;
      int qr = w * 32 + lane;
      mldiag[base + 128 + qr] = lsum;
    }
  } else {
    // producer chunk: bf16 partial (O, l)
    const int PL0 = kh * (kh - 1) + dlt * kh;
    const int e = g * 56 + PL0 + ci;
    char* pp = (e < PART_SPLIT) ? (partsA + (size_t)e * PART_BYTES)
                                : (partsB + (size_t)(e - PART_SPLIT) * PART_BYTES);
    short* po = (short*)pp;
#pragma unroll
    for (int r = 0; r < 16; ++r) {
      int qrow = (r & 3) + 8 * (r >> 2) + 4 * hi5;
      int rr = w * 32 + qrow;
      po[rr * 64 + l31] = f2bf(oacc0[r]);
      po[rr * 64 + 32 + l31] = f2bf(oacc1[r]);
    }
    if (lane < 32) {
      int qr = w * 32 + lane;
      *(float*)(pp + 16896 + qr * 4) = lsum;
    }
  }
}

// ---------- merge partial chunks into vals (plain sums; m == 0) -----------------
// grid (14, 32): p = 2+bx, g = by. 256 thr: row = tid>>1 (128), dh = (tid&1)*32.
__global__ __launch_bounds__(256) void attn_merge3(
    short* __restrict__ vals, const char* __restrict__ partsA,
    const char* __restrict__ partsB, const float* __restrict__ mldiag) {
  const int p = 2 + blockIdx.x;
  const int g = blockIdx.y;
  const int k = p >> 1, dlt = p & 1;
  const int np = k;                       // producers = cnt-1
  const int PL = k * (k - 1) + dlt * k;
  const int e0 = g * 56 + PL;
  const int tid = threadIdx.x;
  const int row = tid >> 1;
  const int dh = (tid & 1) << 5;

  float lacc = mldiag[(g * 16 + p) * 256 + 128 + row];

  size_t vbase = ((size_t)g * TT + p * 128 + row) * HDD + dh;
  float o[32];
  {
    short8 v0 = *(const short8*)(vals + vbase);
    short8 v1 = *(const short8*)(vals + vbase + 8);
    short8 v2 = *(const short8*)(vals + vbase + 16);
    short8 v3 = *(const short8*)(vals + vbase + 24);
#pragma unroll
    for (int jj = 0; jj < 8; ++jj) {
      o[jj] = bf2f(v0[jj]);
      o[8 + jj] = bf2f(v1[jj]);
      o[16 + jj] = bf2f(v2[jj]);
      o[24 + jj] = bf2f(v3[jj]);
    }
  }
  for (int e = 0; e < np; ++e) {
    int ee = e0 + e;
    const char* pp = (ee < PART_SPLIT)
                         ? (partsA + (size_t)ee * PART_BYTES)
                         : (partsB + (size_t)(ee - PART_SPLIT) * PART_BYTES);
    lacc += *(const float*)(pp + 16896 + row * 4);
    const short* po = (const short*)pp + row * 64 + dh;
    short8 v0 = *(const short8*)po;
    short8 v1 = *(const short8*)(po + 8);
    short8 v2 = *(const short8*)(po + 16);
    short8 v3 = *(const short8*)(po + 24);
#pragma unroll
    for (int jj = 0; jj < 8; ++jj) {
      o[jj] += bf2f(v0[jj]);
      o[8 + jj] += bf2f(v1[jj]);
      o[16 + jj] += bf2f(v2[jj]);
      o[24 + jj] += bf2f(v3[jj]);
    }
  }
  float inv = 1.f / lacc;
  short8 w0, w1, w2, w3;
#pragma unroll
  for (int jj = 0; jj < 8; ++jj) {
    w0[jj] = f2bf(o[jj] * inv);
    w1[jj] = f2bf(o[8 + jj] * inv);
    w2[jj] = f2bf(o[16 + jj] * inv);
    w3[jj] = f2bf(o[24 + jj] * inv);
  }
  *(short8*)(vals + vbase) = w0;
  *(short8*)(vals + vbase + 8) = w1;
  *(short8*)(vals + vbase + 16) = w2;
  *(short8*)(vals + vbase + 24) = w3;
}

extern "C" void kernel_launch(void* const* d_in, const int* in_sizes, int n_in,
                              void* d_out, int out_size, void* d_ws, size_t ws_size,
                              hipStream_t stream) {
  const float* x     = (const float*)d_in[0];   // (B, T, D)
  const float* w_qkv = (const float*)d_in[1];   // (D, 3D)
  const float* w_out = (const float*)d_in[2];   // (D, D)
  float* out = (float*)d_out;                   // (B, T, D) fp32

  // workspace layout (bytes)
  char* ws = (char*)d_ws;
  short* qkvb  = (short*)(ws);                       // 25.17 MB
  short* valsb = (short*)(ws + 25165824);            //  8.39 MB
  short* xb    = (short*)(ws + 33554432);            //  8.39 MB (dead after gemm1)
  short* wqkvT = (short*)(ws + 41943040);            //  6.29 MB (dead after gemm1)
  short* woutT = (short*)(ws + 48234496);            //  2.10 MB
  short* vtg   = (short*)(ws + 50331648);            //  8.39 MB (V^T [g][d][t])
  char*  partsA = ws + 33554432;                     // 14.67 MB (over xb/wqkvT)
  char*  partsB = (char*)d_out;                      // d_out scratch pre-gemm2
  float* mldiag = (float*)(ws + 58720256);           //  0.50 MB

  const int M = BB * TT;  // 4096

  // 1) prep: x->bf16 + both weight transposes
  prep<<<6144, 256, 0, stream>>>(x, w_qkv, w_out, xb, wqkvT, woutT);

  // 2) qkv = x @ w_qkv (bf16 out)
  gemm_bf16_mfma<true><<<(M / 128) * (3 * DD / 128), 256, 0, stream>>>(
      xb, wqkvT, qkvb, M, 3 * DD, DD);

  // 3) V^T precompute
  {
    dim3 g(TT / 64, HH, BB);
    vtrans<<<g, 256, 0, stream>>>(qkvb, vtg);
  }

  // 4) flash attention + merge (separate kernel: device-wide sync boundary)
  attn_flash8<<<2304, 256, 0, stream>>>(qkvb, vtg, valsb, partsA, partsB, mldiag);
  {
    dim3 g(14, 32);
    attn_merge3<<<g, 256, 0, stream>>>(valsb, partsA, partsB, mldiag);
  }

  // 5) out = vals @ w_out (fp32 out)
  gemm_bf16_mfma<false><<<(M / 128) * (DD / 128), 256, 0, stream>>>(
      valsb, woutT, out, M, DD, DD);
}